// Round 5
// baseline (198938.611 us; speedup 1.0000x reference)
//
#include <hip/hip_runtime.h>
#include <hip/hip_bf16.h>
#include <math.h>

// Problem constants (B=32, Ts=64, Tt=66, E=H=512, V=16000)
#define TSRC 64
#define TTRG 66
#define NVOC 15996   // V-4

__device__ __forceinline__ float sigm(float x){ return 1.f/(1.f+expf(-x)); }

// ---------------------------------------------------------------------------
// Naive GEMM: C[z][m][n] = sum_k A[z][m][k] * B[z][n][k] (+bias[n]).
// One thread per output element. Batch via blockIdx.y with strides.
// ---------------------------------------------------------------------------
__global__ __launch_bounds__(256)
void k_ngemm(const float* __restrict__ A, long sA, int lda,
             const float* __restrict__ B, long sB, int ldb,
             const float* __restrict__ bias,
             float* __restrict__ C, long sC, int ldc,
             int M, int N, int K)
{
  long idx = (long)blockIdx.x*256 + threadIdx.x;
  if (idx >= (long)M*N) return;
  int m = (int)(idx / N), n = (int)(idx % N);
  const float* a = A + (long)blockIdx.y*sA + (long)m*lda;
  const float* b = B + (long)blockIdx.y*sB + (long)n*ldb;
  float s = bias ? bias[n] : 0.f;
  for (int k=0;k<K;k++) s = fmaf(a[k], b[k], s);
  C[(long)blockIdx.y*sC + (long)m*ldc + n] = s;
}

// Embedding gather: out[(t*32+b)*512 + e] = emb[tok[b*Tfull + t]*512 + e]
__global__ void k_gather(const float* __restrict__ emb, const int* __restrict__ tok,
                         float* __restrict__ outp, int Tfull)
{
  int r = blockIdx.x;            // r = t*32 + b, r < 2048
  int t = r >> 5, b = r & 31;
  int token = tok[b*Tfull + t];
  const float4* s = (const float4*)(emb + (long)token*512);
  float4* d = (float4*)(outp + (long)r*512);
  d[threadIdx.x] = s[threadIdx.x];   // 128 threads * float4 = 512 floats
}

// Encoder LSTM pointwise update (both directions), single gates buffer.
// gates: [2 dirs][32][2048] recurrent part; xg: [t*32+b][4096] input part+bias
__global__ __launch_bounds__(256)
void k_enc_update(const float* __restrict__ gates, const float* __restrict__ xg,
                  float* __restrict__ c, float* __restrict__ hout,
                  float* __restrict__ xout, int tf, int tb, int mode)
{
  int tid = blockIdx.x*256 + threadIdx.x;   // 32768 total
  int jh  = tid & 511;
  int b   = (tid >> 9) & 31;
  int dir = tid >> 14;
  int t   = dir ? tb : tf;
  const float* g0 = gates + (long)dir*65536 + (long)b*2048;
  const float* x  = xg + ((long)t*32 + b)*4096 + dir*2048;
  float gi = g0[jh]      + x[jh];
  float gf = g0[512+jh]  + x[512+jh];
  float gg = g0[1024+jh] + x[1024+jh];
  float go = g0[1536+jh] + x[1536+jh];
  long ci = ((long)dir*32 + b)*512 + jh;
  float cn = sigm(gf)*c[ci] + sigm(gi)*tanhf(gg);
  float hn = sigm(go)*tanhf(cn);
  c[ci] = cn;
  hout[ci] = hn;
  if (mode == 0) xout[((long)t*32 + b)*1024 + dir*512 + jh] = hn;   // x1
  else           xout[((long)b*64 + t)*1024 + dir*512 + jh] = hn;   // enc_out
}

// Pack layer-0 final states into decoder initial h/c: [32][1024] = [fwd|bwd]
__global__ void k_pack(const float* __restrict__ hfin, const float* __restrict__ cfin,
                       float* __restrict__ dh, float* __restrict__ dcc)
{
  int tid = blockIdx.x*256 + threadIdx.x;   // 32768
  int j = tid & 1023, b = tid >> 10;
  int dir = j >> 9, jj = j & 511;
  long si = ((long)dir*32 + b)*512 + jj;
  dh[(long)b*1024 + j]  = hfin[si];
  dcc[(long)b*1024 + j] = cfin[si];
}

// Decoder: fused LSTM update + PAD mask + dot attention + context.
__global__ __launch_bounds__(256)
void k_dec_step(const float* __restrict__ gates, const float* __restrict__ xgd_t,
                float* __restrict__ c, float* __restrict__ hout, float* __restrict__ hctx,
                const float* __restrict__ encout, const int* __restrict__ src,
                const int* __restrict__ trg, int step)
{
  int b = blockIdx.x, tid = threadIdx.x;
  __shared__ float sh[1024];
  __shared__ float ssc[64];
  int tgt = trg[b*TTRG + step + 1];
  bool dm = (tgt == 0);
  const float* g0 = gates + (long)b*4096;
  const float* xr = xgd_t + (long)b*4096;
  for (int r=0;r<4;r++) {
    int jh = tid + 256*r;
    float gi = g0[jh]      + xr[jh];
    float gf = g0[1024+jh] + xr[1024+jh];
    float gg = g0[2048+jh] + xr[2048+jh];
    float go = g0[3072+jh] + xr[3072+jh];
    float co = c[(long)b*1024 + jh];
    float cn = sigm(gf)*co + sigm(gi)*tanhf(gg);
    float hn = sigm(go)*tanhf(cn);
    c[(long)b*1024 + jh] = cn;          // cell NOT masked (matches reference)
    hn = dm ? 0.f : hn;                 // h masked before attention & carry
    hout[(long)b*1024 + jh] = hn;
    hctx[(long)b*2048 + jh] = hn;
    sh[jh] = hn;
  }
  __syncthreads();
  if (tid < 64) {
    const float* eo = encout + ((long)b*64 + tid)*1024;
    float s = 0.f;
    for (int k=0;k<1024;k++) s = fmaf(sh[k], eo[k], s);
    ssc[tid] = (src[b*TSRC + tid] == 0) ? -1e9f : s;
  }
  __syncthreads();
  if (tid == 0) {     // single-thread softmax over 64
    float m = -3.4e38f;
    for (int t=0;t<64;t++) m = fmaxf(m, ssc[t]);
    float su = 0.f;
    for (int t=0;t<64;t++) su += expf(ssc[t]-m);
    for (int t=0;t<64;t++) ssc[t] = expf(ssc[t]-m)/su;
  }
  __syncthreads();
  for (int r=0;r<4;r++) {
    int k = tid + 256*r;
    float acc = 0.f;
    const float* eb = encout + (long)b*65536 + k;
    for (int t=0;t<64;t++) acc = fmaf(ssc[t], eb[t*1024], acc);
    hctx[(long)b*2048 + 1024 + k] = acc;
  }
}

__global__ void k_tanh(float* __restrict__ v)
{
  int i = blockIdx.x*256 + threadIdx.x;  // 16384
  v[i] = tanhf(v[i]);
}

// Per-row: argmax (first-index ties), log-sum-exp, NLL, pred (f32 out).
__global__ __launch_bounds__(256)
void k_row_reduce(const float* __restrict__ logits, const int* __restrict__ trg,
                  int step, float* __restrict__ nll, float* __restrict__ outp)
{
  int b = blockIdx.x, tid = threadIdx.x;
  const float* L = logits + (long)b*NVOC;
  __shared__ float sm[256]; __shared__ int si[256]; __shared__ float ssum[256];
  float bm = -3.4e38f; int bi = 1<<30;
  for (int v=tid; v<NVOC; v+=256) {
    float x = L[v];
    if (x > bm || (x == bm && v < bi)) { bm = x; bi = v; }
  }
  sm[tid]=bm; si[tid]=bi; __syncthreads();
  for (int off=128; off; off>>=1) {
    if (tid < off) {
      float xm = sm[tid+off]; int xi = si[tid+off];
      if (xm > sm[tid] || (xm == sm[tid] && xi < si[tid])) { sm[tid]=xm; si[tid]=xi; }
    }
    __syncthreads();
  }
  bm = sm[0]; int amax = si[0];
  float se = 0.f;
  for (int v=tid; v<NVOC; v+=256) se += expf(L[v] - bm);
  ssum[tid]=se; __syncthreads();
  for (int off=128; off; off>>=1) { if (tid<off) ssum[tid]+=ssum[tid+off]; __syncthreads(); }
  if (tid == 0) {
    int tgt = trg[b*TTRG + step + 1];
    float nl = 0.f;
    if (tgt != 0) {
      int ti = tgt - 4;
      nl = -(L[ti] - bm - logf(ssum[0]));
    }
    nll[step*32 + b] = nl;
    outp[1 + b*64 + step] = (float)(amax + 4);   // f32 output
  }
}

// Final: loss = sum(nll)/denom  (f32 out)
__global__ __launch_bounds__(256)
void k_final(const float* __restrict__ nll, const int* __restrict__ trg,
             float* __restrict__ outp)
{
  int tid = threadIdx.x;
  __shared__ float ss[256]; __shared__ int sc[256];
  float s = 0.f; int cnt = 0;
  for (int i=tid; i<2048; i+=256) {
    s += nll[i];
    int b = i >> 6, t = (i & 63) + 1;
    cnt += (trg[b*TTRG + t] != 0);
  }
  ss[tid]=s; sc[tid]=cnt; __syncthreads();
  for (int off=128; off; off>>=1) {
    if (tid<off) { ss[tid]+=ss[tid+off]; sc[tid]+=sc[tid+off]; }
    __syncthreads();
  }
  if (tid==0) outp[0] = ss[0] / (float)sc[0];
}

// ---------------------------------------------------------------------------
static void ngemm(hipStream_t st, const float* A, long sA, int lda,
                  const float* B, long sB, int ldb, const float* bias,
                  float* C, long sC, int ldc, int M, int N, int K, int batch)
{
  long tot = (long)M*N;
  dim3 g((unsigned)((tot + 255)/256), batch, 1);
  k_ngemm<<<g, dim3(256), 0, st>>>(A, sA, lda, B, sB, ldb, bias, C, sC, ldc, M, N, K);
}

extern "C" void kernel_launch(void* const* d_in, const int* in_sizes, int n_in,
                              void* d_out, int out_size, void* d_ws, size_t ws_size,
                              hipStream_t stream)
{
  (void)in_sizes; (void)n_in; (void)out_size; (void)ws_size;
  const int*   src   = (const int*)  d_in[0];
  const int*   trg   = (const int*)  d_in[1];
  const float* semb  = (const float*)d_in[2];
  const float* temb  = (const float*)d_in[3];
  const float* e0Wih = (const float*)d_in[4];
  const float* e0Whh = (const float*)d_in[5];
  const float* e0b   = (const float*)d_in[6];
  const float* e1Wih = (const float*)d_in[7];
  const float* e1Whh = (const float*)d_in[8];
  const float* e1b   = (const float*)d_in[9];
  const float* dWih  = (const float*)d_in[10];
  const float* dWhh  = (const float*)d_in[11];
  const float* db    = (const float*)d_in[12];
  const float* W1    = (const float*)d_in[13];
  const float* W2    = (const float*)d_in[14];
  float* out = (float*)d_out;   // f32 output (confirmed by round-4 diagnostic)

  float* ws = (float*)d_ws;
  size_t o = 0;
  float* x_in   = ws + o; o += (size_t)2048*512;
  float* xg     = ws + o; o += (size_t)2048*4096;
  float* x1     = ws + o; o += (size_t)2048*1024;
  float* encout = ws + o; o += (size_t)32*64*1024;
  float* hA     = ws + o; o += 2*32*512;
  float* hB     = ws + o; o += 2*32*512;
  float* cbuf   = ws + o; o += 2*32*512;
  float* gates  = ws + o; o += 2*65536;
  float* dhA    = ws + o; o += 32*1024;
  float* dhB    = ws + o; o += 32*1024;
  float* dc     = ws + o; o += 32*1024;
  float* hctx   = ws + o; o += 32*2048;
  float* zt     = ws + o; o += 16384;
  float* logits = ws + o; o += 511872;
  float* nll    = ws + o; o += 2048;

  // ---- encoder layer 0 ----
  hipMemsetAsync(hA,   0, 2*32*512*sizeof(float), stream);
  hipMemsetAsync(cbuf, 0, 2*32*512*sizeof(float), stream);
  k_gather<<<dim3(2048), dim3(128), 0, stream>>>(semb, src, x_in, TSRC);
  ngemm(stream, x_in, 0, 512, e0Wih, 0, 512, e0b, xg, 0, 4096, 2048, 4096, 512, 1);
  for (int s=0; s<64; s++) {
    float* hin  = (s&1) ? hB : hA;
    float* hout = (s&1) ? hA : hB;
    ngemm(stream, hin, 32*512, 512, e0Whh, (long)2048*512, 512, nullptr,
          gates, 65536, 2048, 32, 2048, 512, 2);
    k_enc_update<<<dim3(128), dim3(256), 0, stream>>>(gates, xg, cbuf, hout, x1, s, 63-s, 0);
  }
  k_pack<<<dim3(128), dim3(256), 0, stream>>>(hA, cbuf, dhA, dc);

  // ---- encoder layer 1 ----
  hipMemsetAsync(hA,   0, 2*32*512*sizeof(float), stream);
  hipMemsetAsync(cbuf, 0, 2*32*512*sizeof(float), stream);
  ngemm(stream, x1, 0, 1024, e1Wih, 0, 1024, e1b, xg, 0, 4096, 2048, 4096, 1024, 1);
  for (int s=0; s<64; s++) {
    float* hin  = (s&1) ? hB : hA;
    float* hout = (s&1) ? hA : hB;
    ngemm(stream, hin, 32*512, 512, e1Whh, (long)2048*512, 512, nullptr,
          gates, 65536, 2048, 32, 2048, 512, 2);
    k_enc_update<<<dim3(128), dim3(256), 0, stream>>>(gates, xg, cbuf, hout, encout, s, 63-s, 1);
  }

  // ---- decoder ----
  k_gather<<<dim3(2048), dim3(128), 0, stream>>>(temb, trg, x_in, TTRG);
  ngemm(stream, x_in, 0, 512, dWih, 0, 512, db, xg, 0, 4096, 2048, 4096, 512, 1);
  for (int st=0; st<64; st++) {
    float* hin  = (st&1) ? dhB : dhA;
    float* hout = (st&1) ? dhA : dhB;
    ngemm(stream, hin, 0, 1024, dWhh, 0, 1024, nullptr, gates, 0, 4096, 32, 4096, 1024, 1);
    k_dec_step<<<dim3(32), dim3(256), 0, stream>>>(gates, xg + (size_t)st*32*4096,
                 dc, hout, hctx, encout, src, trg, st);
    ngemm(stream, hctx, 0, 2048, W1, 0, 2048, nullptr, zt, 0, 512, 32, 512, 2048, 1);
    k_tanh<<<dim3(64), dim3(256), 0, stream>>>(zt);
    ngemm(stream, zt, 0, 512, W2, 0, 512, nullptr, logits, 0, NVOC, 32, NVOC, 512, 1);
    k_row_reduce<<<dim3(32), dim3(256), 0, stream>>>(logits, trg, st, nll, out);
  }
  k_final<<<dim3(1), dim3(256), 0, stream>>>(nll, trg, out);
}

// Round 6
// 14264.291 us; speedup vs baseline: 13.9466x; 13.9466x over previous
//
#include <hip/hip_runtime.h>
#include <hip/hip_bf16.h>
#include <math.h>

// Problem constants (B=32, Ts=64, Tt=66, E=H=512, V=16000)
#define TSRC 64
#define TTRG 66
#define NVOC 15996   // V-4

__device__ __forceinline__ float sigm(float x){ return 1.f/(1.f+expf(-x)); }

// ---------------------------------------------------------------------------
// Tiled GEMM: C = A[M,K] * B[N,K]^T (+bias). Batch via z, K-split via y
// (partial slabs at C + y*sKC; bias only applied when ksplit==1).
// ---------------------------------------------------------------------------
struct GArgs {
  const float* A;  long sA; int lda;
  const float* Bw; long sB; int ldb;
  const float* bias;
  float* C; long sC; int ldc; long sKC;
  int N; int KC; int nNb;
};

template<int BM,int BN,int BK,int TM,int TN>
__global__ __launch_bounds__(256)
void k_gemm(GArgs a)
{
  const int tid = threadIdx.x;
  const int mb = blockIdx.x / a.nNb;
  const int nb = blockIdx.x % a.nNb;
  const int m0 = mb*BM, n0 = nb*BN;
  const long k0 = (long)blockIdx.y * a.KC;
  const float* A  = a.A  + (long)blockIdx.z*a.sA + (long)m0*a.lda + k0;
  const float* Bw = a.Bw + (long)blockIdx.z*a.sB + k0;
  float* C = a.C + (long)blockIdx.z*a.sC + (long)blockIdx.y*a.sKC;

  __shared__ float As[BK][BM+1];
  __shared__ float Bs[BK][BN+4];
  const int tx = tid % (BN/TN);
  const int ty = tid / (BN/TN);
  float acc[TM][TN];
  #pragma unroll
  for (int i=0;i<TM;i++)
    #pragma unroll
    for (int j=0;j<TN;j++) acc[i][j]=0.f;

  for (int kt=0; kt<a.KC; kt+=BK) {
    #pragma unroll
    for (int i=tid; i<BM*BK; i+=256) {
      int m = i/BK, k = i%BK;
      As[k][m] = A[(long)m*a.lda + kt + k];
    }
    #pragma unroll
    for (int i=tid; i<BN*BK; i+=256) {
      int n = i/BK, k = i%BK;
      int gn = n0+n;
      Bs[k][n] = (gn < a.N) ? Bw[(long)gn*a.ldb + kt + k] : 0.f;
    }
    __syncthreads();
    #pragma unroll
    for (int k=0;k<BK;k++) {
      float av[TM], bv[TN];
      #pragma unroll
      for (int i=0;i<TM;i++) av[i]=As[k][ty*TM+i];
      #pragma unroll
      for (int j=0;j<TN;j++) bv[j]=Bs[k][tx*TN+j];
      #pragma unroll
      for (int i=0;i<TM;i++)
        #pragma unroll
        for (int j=0;j<TN;j++)
          acc[i][j] = fmaf(av[i], bv[j], acc[i][j]);
    }
    __syncthreads();
  }
  #pragma unroll
  for (int i=0;i<TM;i++) {
    int m = m0 + ty*TM + i;
    #pragma unroll
    for (int j=0;j<TN;j++) {
      int n = n0 + tx*TN + j;
      if (n < a.N) {
        float v = acc[i][j];
        if (a.bias) v += a.bias[n];
        C[(long)m*a.ldc + n] = v;
      }
    }
  }
}

// Embedding gather: out[(t*32+b)*512 + e] = emb[tok[b*Tfull + t]*512 + e]
__global__ void k_gather(const float* __restrict__ emb, const int* __restrict__ tok,
                         float* __restrict__ outp, int Tfull)
{
  int r = blockIdx.x;            // r = t*32 + b, r < 2048
  int t = r >> 5, b = r & 31;
  int token = tok[b*Tfull + t];
  const float4* s = (const float4*)(emb + (long)token*512);
  float4* d = (float4*)(outp + (long)r*512);
  d[threadIdx.x] = s[threadIdx.x];   // 128 threads * float4 = 512 floats
}

// Encoder LSTM pointwise update (both directions).
// gates: 2 K-split slabs of [2 dirs][32][2048]; xg: [t*32+b][4096] incl bias
__global__ __launch_bounds__(256)
void k_enc_update(const float* __restrict__ gates, const float* __restrict__ xg,
                  float* __restrict__ c, float* __restrict__ hout,
                  float* __restrict__ xout, int tf, int tb, int mode)
{
  int tid = blockIdx.x*256 + threadIdx.x;   // 32768 total
  int jh  = tid & 511;
  int b   = (tid >> 9) & 31;
  int dir = tid >> 14;
  int t   = dir ? tb : tf;
  const float* g0 = gates + (long)dir*65536 + (long)b*2048;
  const float* g1 = g0 + 131072;
  const float* x  = xg + ((long)t*32 + b)*4096 + dir*2048;
  float gi = g0[jh]      + g1[jh]      + x[jh];
  float gf = g0[512+jh]  + g1[512+jh]  + x[512+jh];
  float gg = g0[1024+jh] + g1[1024+jh] + x[1024+jh];
  float go = g0[1536+jh] + g1[1536+jh] + x[1536+jh];
  long ci = ((long)dir*32 + b)*512 + jh;
  float cn = sigm(gf)*c[ci] + sigm(gi)*tanhf(gg);
  float hn = sigm(go)*tanhf(cn);
  c[ci] = cn;
  hout[ci] = hn;
  if (mode == 0) xout[((long)t*32 + b)*1024 + dir*512 + jh] = hn;   // x1
  else           xout[((long)b*64 + t)*1024 + dir*512 + jh] = hn;   // enc_out
}

// Pack layer-0 final states into decoder initial h/c: [32][1024] = [fwd|bwd]
__global__ void k_pack(const float* __restrict__ hfin, const float* __restrict__ cfin,
                       float* __restrict__ dh, float* __restrict__ dcc)
{
  int tid = blockIdx.x*256 + threadIdx.x;   // 32768
  int j = tid & 1023, b = tid >> 10;
  int dir = j >> 9, jj = j & 511;
  long si = ((long)dir*32 + b)*512 + jj;
  dh[(long)b*1024 + j]  = hfin[si];
  dcc[(long)b*1024 + j] = cfin[si];
}

// Decoder: fused LSTM update + PAD mask + dot attention + context.
// gates: 2 K-split slabs of [32][4096].
__global__ __launch_bounds__(256)
void k_dec_step(const float* __restrict__ gates, const float* __restrict__ xgd_t,
                float* __restrict__ c, float* __restrict__ hout, float* __restrict__ hctx,
                const float* __restrict__ encout, const int* __restrict__ src,
                const int* __restrict__ trg, int step)
{
  int b = blockIdx.x, tid = threadIdx.x;
  __shared__ float sh[1024];
  __shared__ float ssc[64];
  int tgt = trg[b*TTRG + step + 1];
  bool dm = (tgt == 0);
  const float* g0 = gates + (long)b*4096;
  const float* g1 = g0 + 131072;
  const float* xr = xgd_t + (long)b*4096;
  for (int r=0;r<4;r++) {
    int jh = tid + 256*r;
    float gi = g0[jh]      + g1[jh]      + xr[jh];
    float gf = g0[1024+jh] + g1[1024+jh] + xr[1024+jh];
    float gg = g0[2048+jh] + g1[2048+jh] + xr[2048+jh];
    float go = g0[3072+jh] + g1[3072+jh] + xr[3072+jh];
    float co = c[(long)b*1024 + jh];
    float cn = sigm(gf)*co + sigm(gi)*tanhf(gg);
    float hn = sigm(go)*tanhf(cn);
    c[(long)b*1024 + jh] = cn;          // cell NOT masked (matches reference)
    hn = dm ? 0.f : hn;                 // h masked before attention & carry
    hout[(long)b*1024 + jh] = hn;
    hctx[(long)b*2048 + jh] = hn;
    sh[jh] = hn;
  }
  __syncthreads();
  // scores: 4 threads per t'
  {
    int tq = tid >> 2, part = tid & 3;
    const float* eo = encout + ((long)b*64 + tq)*1024 + part*256;
    const float* hh = sh + part*256;
    float s = 0.f;
    for (int k=0;k<256;k++) s = fmaf(hh[k], eo[k], s);
    s += __shfl_xor(s, 1);
    s += __shfl_xor(s, 2);
    if (part == 0) ssc[tq] = (src[b*TSRC + tq] == 0) ? -1e9f : s;
  }
  __syncthreads();
  if (tid < 64) {   // softmax over 64 scores, one wave
    float v = ssc[tid];
    float m = v;
    for (int d=1; d<64; d<<=1) m = fmaxf(m, __shfl_xor(m, d));
    float e = expf(v - m);
    float su = e;
    for (int d=1; d<64; d<<=1) su += __shfl_xor(su, d);
    ssc[tid] = e / su;
  }
  __syncthreads();
  for (int r=0;r<4;r++) {
    int k = tid + 256*r;
    float acc = 0.f;
    const float* eb = encout + (long)b*65536 + k;
    for (int t=0;t<64;t++) acc = fmaf(ssc[t], eb[t*1024], acc);
    hctx[(long)b*2048 + 1024 + k] = acc;
  }
}

// Reduce 8 K-split partials of zt and apply tanh.
__global__ void k_zt_reduce(const float* __restrict__ ztp, float* __restrict__ zt)
{
  int i = blockIdx.x*256 + threadIdx.x;  // 16384
  float s = 0.f;
  #pragma unroll
  for (int p=0;p<8;p++) s += ztp[(long)p*16384 + i];
  zt[i] = tanhf(s);
}

// Per-row: argmax (first-index ties), log-sum-exp, NLL, pred. 2 logits slabs.
__global__ __launch_bounds__(256)
void k_row_reduce(const float* __restrict__ logits, const int* __restrict__ trg,
                  int step, float* __restrict__ nll, float* __restrict__ outp)
{
  int b = blockIdx.x, tid = threadIdx.x;
  const float* L0 = logits + (long)b*NVOC;
  const float* L1 = L0 + 511872;   // K-split slab stride = 32*NVOC
  __shared__ float sm[256]; __shared__ int si[256]; __shared__ float ssum[256];
  float bm = -3.4e38f; int bi = 1<<30;
  for (int v=tid; v<NVOC; v+=256) {
    float x = L0[v] + L1[v];
    if (x > bm || (x == bm && v < bi)) { bm = x; bi = v; }
  }
  sm[tid]=bm; si[tid]=bi; __syncthreads();
  for (int off=128; off; off>>=1) {
    if (tid < off) {
      float xm = sm[tid+off]; int xi = si[tid+off];
      if (xm > sm[tid] || (xm == sm[tid] && xi < si[tid])) { sm[tid]=xm; si[tid]=xi; }
    }
    __syncthreads();
  }
  bm = sm[0]; int amax = si[0];
  float se = 0.f;
  for (int v=tid; v<NVOC; v+=256) se += expf(L0[v] + L1[v] - bm);
  ssum[tid]=se; __syncthreads();
  for (int off=128; off; off>>=1) { if (tid<off) ssum[tid]+=ssum[tid+off]; __syncthreads(); }
  if (tid == 0) {
    int tgt = trg[b*TTRG + step + 1];
    float nl = 0.f;
    if (tgt != 0) {
      int ti = tgt - 4;
      nl = -(L0[ti] + L1[ti] - bm - logf(ssum[0]));
    }
    nll[step*32 + b] = nl;
    outp[1 + b*64 + step] = (float)(amax + 4);   // f32 output
  }
}

// Final: loss = sum(nll)/denom  (f32 out)
__global__ __launch_bounds__(256)
void k_final(const float* __restrict__ nll, const int* __restrict__ trg,
             float* __restrict__ outp)
{
  int tid = threadIdx.x;
  __shared__ float ss[256]; __shared__ int sc[256];
  float s = 0.f; int cnt = 0;
  for (int i=tid; i<2048; i+=256) {
    s += nll[i];
    int b = i >> 6, t = (i & 63) + 1;
    cnt += (trg[b*TTRG + t] != 0);
  }
  ss[tid]=s; sc[tid]=cnt; __syncthreads();
  for (int off=128; off; off>>=1) {
    if (tid<off) { ss[tid]+=ss[tid+off]; sc[tid]+=sc[tid+off]; }
    __syncthreads();
  }
  if (tid==0) outp[0] = ss[0] / (float)sc[0];
}

// ---------------------------------------------------------------------------
static void launch_small(hipStream_t st, const float* A, long sA, int lda,
                         const float* Bw, long sB, int ldb,
                         float* C, long sC, int ldc, long sKC,
                         int N, int K, int ksplit, int batch)
{
  GArgs a;
  a.A=A; a.sA=sA; a.lda=lda;
  a.Bw=Bw; a.sB=sB; a.ldb=ldb;
  a.bias=nullptr;
  a.C=C; a.sC=sC; a.ldc=ldc; a.sKC=sKC;
  a.N=N; a.KC=K/ksplit; a.nNb=(N+63)/64;
  dim3 g(a.nNb, ksplit, batch);
  k_gemm<32,64,16,2,4><<<g, dim3(256), 0, st>>>(a);
}

static void launch_big(hipStream_t st, const float* A, int lda,
                       const float* Bw, int ldb, const float* bias,
                       float* C, int M, int N, int K)
{
  GArgs a;
  a.A=A; a.sA=0; a.lda=lda;
  a.Bw=Bw; a.sB=0; a.ldb=ldb;
  a.bias=bias;
  a.C=C; a.sC=0; a.ldc=N; a.sKC=0;
  a.N=N; a.KC=K; a.nNb=N/128;
  dim3 g((M/128)*(N/128), 1, 1);
  k_gemm<128,128,16,8,8><<<g, dim3(256), 0, st>>>(a);
}

extern "C" void kernel_launch(void* const* d_in, const int* in_sizes, int n_in,
                              void* d_out, int out_size, void* d_ws, size_t ws_size,
                              hipStream_t stream)
{
  (void)in_sizes; (void)n_in; (void)out_size; (void)ws_size;
  const int*   src   = (const int*)  d_in[0];
  const int*   trg   = (const int*)  d_in[1];
  const float* semb  = (const float*)d_in[2];
  const float* temb  = (const float*)d_in[3];
  const float* e0Wih = (const float*)d_in[4];
  const float* e0Whh = (const float*)d_in[5];
  const float* e0b   = (const float*)d_in[6];
  const float* e1Wih = (const float*)d_in[7];
  const float* e1Whh = (const float*)d_in[8];
  const float* e1b   = (const float*)d_in[9];
  const float* dWih  = (const float*)d_in[10];
  const float* dWhh  = (const float*)d_in[11];
  const float* db    = (const float*)d_in[12];
  const float* W1    = (const float*)d_in[13];
  const float* W2    = (const float*)d_in[14];
  float* out = (float*)d_out;   // f32 output (round-4 diagnostic)

  float* ws = (float*)d_ws;
  size_t o = 0;
  float* x_in   = ws + o; o += (size_t)2048*512;
  float* xg     = ws + o; o += (size_t)2048*4096;
  float* x1     = ws + o; o += (size_t)2048*1024;
  float* encout = ws + o; o += (size_t)32*64*1024;
  float* hA     = ws + o; o += 2*32*512;
  float* hB     = ws + o; o += 2*32*512;
  float* cbuf   = ws + o; o += 2*32*512;
  float* gates  = ws + o; o += 2*131072;            // 2 K-split slabs
  float* dhA    = ws + o; o += 32*1024;
  float* dhB    = ws + o; o += 32*1024;
  float* dc     = ws + o; o += 32*1024;
  float* hctx   = ws + o; o += 32*2048;
  float* ztp    = ws + o; o += 8*16384;             // zt K-split partials
  float* zt     = ws + o; o += 16384;
  float* logits = ws + o; o += 2*511872;            // 2 K-split slabs
  float* nll    = ws + o; o += 2048;

  // ---- encoder layer 0 ----
  hipMemsetAsync(hA,   0, 2*32*512*sizeof(float), stream);
  hipMemsetAsync(cbuf, 0, 2*32*512*sizeof(float), stream);
  k_gather<<<dim3(2048), dim3(128), 0, stream>>>(semb, src, x_in, TSRC);
  launch_big(stream, x_in, 512, e0Wih, 512, e0b, xg, 2048, 4096, 512);
  for (int s=0; s<64; s++) {
    float* hin  = (s&1) ? hB : hA;
    float* hout = (s&1) ? hA : hB;
    launch_small(stream, hin, 32*512, 512, e0Whh, (long)2048*512, 512,
                 gates, 65536, 2048, 131072, 2048, 512, 2, 2);
    k_enc_update<<<dim3(128), dim3(256), 0, stream>>>(gates, xg, cbuf, hout, x1, s, 63-s, 0);
  }
  k_pack<<<dim3(128), dim3(256), 0, stream>>>(hA, cbuf, dhA, dc);

  // ---- encoder layer 1 ----
  hipMemsetAsync(hA,   0, 2*32*512*sizeof(float), stream);
  hipMemsetAsync(cbuf, 0, 2*32*512*sizeof(float), stream);
  launch_big(stream, x1, 1024, e1Wih, 1024, e1b, xg, 2048, 4096, 1024);
  for (int s=0; s<64; s++) {
    float* hin  = (s&1) ? hB : hA;
    float* hout = (s&1) ? hA : hB;
    launch_small(stream, hin, 32*512, 512, e1Whh, (long)2048*512, 512,
                 gates, 65536, 2048, 131072, 2048, 512, 2, 2);
    k_enc_update<<<dim3(128), dim3(256), 0, stream>>>(gates, xg, cbuf, hout, encout, s, 63-s, 1);
  }

  // ---- decoder ----
  k_gather<<<dim3(2048), dim3(128), 0, stream>>>(temb, trg, x_in, TTRG);
  launch_big(stream, x_in, 512, dWih, 512, db, xg, 2048, 4096, 512);
  for (int st=0; st<64; st++) {
    float* hin  = (st&1) ? dhB : dhA;
    float* hout = (st&1) ? dhA : dhB;
    launch_small(stream, hin, 0, 1024, dWhh, 0, 1024,
                 gates, 0, 4096, 131072, 4096, 1024, 2, 1);
    k_dec_step<<<dim3(32), dim3(256), 0, stream>>>(gates, xg + (size_t)st*32*4096,
                 dc, hout, hctx, encout, src, trg, st);
    launch_small(stream, hctx, 0, 2048, W1, 0, 2048,
                 ztp, 0, 512, 16384, 512, 2048, 8, 1);
    k_zt_reduce<<<dim3(64), dim3(256), 0, stream>>>(ztp, zt);
    launch_small(stream, zt, 0, 512, W2, 0, 512,
                 logits, 0, NVOC, 511872, NVOC, 512, 2, 1);
    k_row_reduce<<<dim3(32), dim3(256), 0, stream>>>(logits, trg, st, nll, out);
  }
  k_final<<<dim3(1), dim3(256), 0, stream>>>(nll, trg, out);
}